// Round 13
// baseline (158.725 us; speedup 1.0000x reference)
//
#include <hip/hip_runtime.h>
#include <hip/hip_bf16.h>
#include <math.h>

// B=1024, N=22, F_IN=32, T=32, K=3, CHEV=64, TIMEF=64
// x[b,n,f,t]: b-stride 22528, n-stride 1024, f-stride 32

typedef unsigned short u16;
typedef __attribute__((ext_vector_type(8))) short short8;
typedef __attribute__((ext_vector_type(4))) float f32x4;
typedef __attribute__((ext_vector_type(2))) float f32x2;

__device__ __forceinline__ float sigm(float v){ return 1.f/(1.f+expf(-v)); }

__device__ __forceinline__ u16 f2bf(float x){
  __hip_bfloat16 h = __float2bfloat16(x);
  return *reinterpret_cast<u16*>(&h);
}
__device__ __forceinline__ unsigned f2bf2(float lo, float hi){
  return (unsigned)f2bf(lo) | ((unsigned)f2bf(hi) << 16);
}

// ---------------- K_prep (blocks 0..80, 16x16 fragment packing) + supports (block 81) ----
__global__ void k_sup_prep(const float* __restrict__ emb, float* __restrict__ wsT,
                           const float* __restrict__ Theta,
                           const float* __restrict__ tw, const float* __restrict__ tb,
                           const float* __restrict__ rw, const float* __restrict__ rb,
                           u16* __restrict__ thA, u16* __restrict__ wA, float* __restrict__ wsB){
  if (blockIdx.x < 81){
    int tid = blockIdx.x*256 + threadIdx.x;
    if (tid < 6144){
      int j = tid&7, l = (tid>>3)&63, blk = tid>>9;      // blk 0..11
      int ks = blk>>2, ci = blk&3, r = l&15, g = l>>4;
      int kf = 32*ks + 8*g + j, c = 16*ci + r;
      thA[tid] = f2bf(Theta[kf*64 + c]);
    } else if (tid < 20480){
      int e = tid - 6144;
      int j = e&7, l = (e>>3)&63, blk = e>>9;            // blk 0..27
      int ks = blk>>2, oi = blk&3, r = l&15, g = l>>4;
      int k = 32*ks + 8*g + j, o = 16*oi + r;
      float v = (k < 192) ? tw[o*192 + (k&63)*3 + (k>>6)] : rw[o*32 + (k-192)];
      wA[e] = f2bf(v);
    } else if (tid < 20544){
      int o = tid - 20480; wsB[o] = tb[o] + rb[o];
    }
    return;
  }
  __shared__ float M[484];
  __shared__ float T1s[484];
  int tid = threadIdx.x;
  for (int idx=tid; idx<484; idx+=256){
    int n = idx/22, m = idx - (idx/22)*22;
    float s = 0.f;
    for (int j=0;j<22;j++) s += emb[n*22+j]*emb[m*22+j];
    M[idx] = fmaxf(s, 0.f);
  }
  __syncthreads();
  if (tid < 22){
    float mx = -1e30f;
    for (int m=0;m<22;m++) mx = fmaxf(mx, M[tid*22+m]);
    float s = 0.f;
    for (int m=0;m<22;m++) s += expf(M[tid*22+m]-mx);
    float inv = 1.f/s;
    for (int m=0;m<22;m++) T1s[tid*22+m] = expf(M[tid*22+m]-mx)*inv;
  }
  __syncthreads();
  for (int idx=tid; idx<484; idx+=256){
    int n = idx/22, m = idx - (idx/22)*22;
    float s = 0.f;
    for (int p=0;p<22;p++) s += T1s[n*22+p]*T1s[p*22+m];
    wsT[idx]      = T1s[idx];
    wsT[484+idx]  = 2.f*s - ((n==m)?1.f:0.f);
  }
}

// ---------------- K12: attention, x panel register-resident (ONE HBM pass) ----------------
// Thread owns (f = tid>>4, t-pair = tid&15); xr[22] holds x[n][f][2tp..2tp+1] in VGPRs.
// Phase 1: thread-local. Phase 2: in-wave shfl f-reduce + 8-wave LDS combine (2 n-chunks).
// Phase 8: in-wave shfl t-reduce (free). Phases 3-7, 9-13 unchanged from R12.
__global__ __launch_bounds__(512, 4) void k_attn(
    const float* __restrict__ x,
    const float* __restrict__ U1, const float* __restrict__ U2, const float* __restrict__ U3,
    const float* __restrict__ be, const float* __restrict__ Ve,
    const float* __restrict__ W1, const float* __restrict__ W2, const float* __restrict__ W3,
    const float* __restrict__ bs, const float* __restrict__ Vs,
    float* __restrict__ snorm){
  int b = blockIdx.x, tid = threadIdx.x;
  const float* xb = x + (size_t)b*22528;
  __shared__ float xu1[1024];
  __shared__ float rhs_t[704];
  __shared__ float lhs_t[704];
  __shared__ float sigp[1024];
  __shared__ float Em[1024];
  __shared__ float sm[1024];
  __shared__ float w1e[32];
  __shared__ float xw3[704];
  __shared__ float lhsS[704];
  __shared__ float lhs2[704];
  __shared__ float rhsS[704];
  __shared__ float sig2[484];
  __shared__ float Sl[484];
  __shared__ __align__(16) float4 part[1408];   // [w8][11][16tp] (rhs.x, rhs.y, xw.x, xw.y)

  int f = tid>>4, tp = tid&15, w8 = tid>>6;

  // ---- single HBM pass: x[n][f][2tp..2tp+1] -> registers ----
  f32x2 xr[22];
  #pragma unroll
  for (int n=0;n<22;n++) xr[n] = *(const f32x2*)&xb[n*1024 + f*32 + 2*tp];

  // ---- phase 1: xu1[f][t] = sum_n xr[n]*U1[n] (thread-local) ----
  {
    f32x2 a = {0.f,0.f};
    #pragma unroll
    for (int n=0;n<22;n++){
      float u = U1[n];
      a[0] = fmaf(xr[n][0], u, a[0]);
      a[1] = fmaf(xr[n][1], u, a[1]);
    }
    *(f32x2*)&xu1[f*32 + 2*tp] = a;
  }

  // ---- phase 2: rhs_t/xw3[n][t] = sum_f xr*U3[f] / xr*W3[f] (shfl f-reduce + combine) ----
  {
    float u3 = U3[f], w3v = W3[f];
    #pragma unroll
    for (int c=0;c<2;c++){
      #pragma unroll
      for (int j=0;j<11;j++){
        int n = c*11 + j;
        float rx = xr[n][0]*u3,  ry = xr[n][1]*u3;
        float wx = xr[n][0]*w3v, wy = xr[n][1]*w3v;
        rx += __shfl_xor(rx,16); rx += __shfl_xor(rx,32);
        ry += __shfl_xor(ry,16); ry += __shfl_xor(ry,32);
        wx += __shfl_xor(wx,16); wx += __shfl_xor(wx,32);
        wy += __shfl_xor(wy,16); wy += __shfl_xor(wy,32);
        if ((tid&63) < 16){
          float4 v; v.x=rx; v.y=ry; v.z=wx; v.w=wy;
          part[(w8*11 + j)*16 + tp] = v;
        }
      }
      __syncthreads();
      if (tid < 352){
        int nl = tid>>5, t = tid&31;
        int tpp = t>>1, lh = t&1;
        float sr = 0.f, sw = 0.f;
        #pragma unroll
        for (int w=0;w<8;w++){
          float4 v = part[(w*11 + nl)*16 + tpp];
          sr += lh ? v.y : v.x;
          sw += lh ? v.w : v.z;
        }
        rhs_t[(c*11+nl)*32 + t] = sr;
        xw3 [(c*11+nl)*32 + t] = sw;
      }
      __syncthreads();
    }
  }

  // ---- phase 3: lhs_t[t][n2] = sum_f xu1[f][t]*U2[f][n2] ----
  if (tid < 352){
    int t = tid&31, np = tid>>5;
    int n2 = np*2;
    f32x2 a = {0.f,0.f};
    #pragma unroll 4
    for (int ff=0;ff<32;ff++){
      float bc = xu1[ff*32+t];
      f32x2 u2 = *(const f32x2*)&U2[ff*22+n2];
      a[0] = fmaf(bc, u2[0], a[0]); a[1] = fmaf(bc, u2[1], a[1]);
    }
    *(f32x2*)&lhs_t[t*22+n2] = a;
  }
  __syncthreads();
  // ---- phase 4: sigp[s][u] = sigm(lhs_t[s][:]·rhs_t[:][u] + be) ----
  {
    int s = tid>>4, u = (tid&15)*2;
    f32x2 p = {0.f,0.f};
    #pragma unroll 2
    for (int n=0;n<22;n++){
      float lv = lhs_t[s*22+n];
      f32x2 rv = *(const f32x2*)&rhs_t[n*32+u];
      p[0] = fmaf(lv, rv[0], p[0]); p[1] = fmaf(lv, rv[1], p[1]);
    }
    f32x2 be2 = *(const f32x2*)&be[s*32+u];
    sigp[s*32+u]   = sigm(p[0] + be2[0]);
    sigp[s*32+u+1] = sigm(p[1] + be2[1]);
  }
  __syncthreads();
  // ---- phase 5: Em[t][u] = sum_s2 Ve[t][s2]*sigp[s2][u] ----
  {
    int t = tid>>4, u = (tid&15)*2;
    f32x2 a = {0.f,0.f};
    #pragma unroll 4
    for (int s2=0;s2<32;s2++){
      float vv = Ve[t*32+s2];
      f32x2 sp = *(const f32x2*)&sigp[s2*32+u];
      a[0] = fmaf(vv, sp[0], a[0]); a[1] = fmaf(vv, sp[1], a[1]);
    }
    *(f32x2*)&Em[t*32+u] = a;
  }
  __syncthreads();
  // ---- temporal softmax over t (axis=1) ----
  {
    int u = tid>>4, th = tid&15;
    float e0 = Em[(2*th)*32 + u], e1 = Em[(2*th+1)*32 + u];
    float mx = fmaxf(e0, e1);
    #pragma unroll
    for (int mask=1; mask<16; mask<<=1) mx = fmaxf(mx, __shfl_xor(mx, mask));
    float x0 = expf(e0-mx), x1 = expf(e1-mx);
    float s = x0 + x1;
    #pragma unroll
    for (int mask=1; mask<16; mask<<=1) s += __shfl_xor(s, mask);
    float inv = 1.f/s;
    sm[(2*th)*32 + u]   = x0*inv;
    sm[(2*th+1)*32 + u] = x1*inv;
  }
  __syncthreads();
  {
    int u = tid>>4, th = tid&15;
    float pw = fmaf(sm[u*32 + 2*th], W1[2*th], sm[u*32 + 2*th+1]*W1[2*th+1]);
    #pragma unroll
    for (int mask=1; mask<16; mask<<=1) pw += __shfl_xor(pw, mask);
    if (th==0) w1e[u] = pw;
  }
  __syncthreads();
  // ---- phase 8: lhsS[n][f] = sum_t xr[n]·w1e (in-wave t-reduce, no HBM re-read) ----
  {
    f32x2 wv = *(const f32x2*)&w1e[2*tp];
    #pragma unroll
    for (int n=0;n<22;n++){
      float s = fmaf(xr[n][0], wv[0], xr[n][1]*wv[1]);
      s += __shfl_xor(s,1); s += __shfl_xor(s,2);
      s += __shfl_xor(s,4); s += __shfl_xor(s,8);
      if (tp == 0) lhsS[n*32 + f] = s;
    }
  }
  __syncthreads();
  // ---- phase 9: lhs2[n][t] = sum_f lhsS[n][f]*W2[f][t] ----
  if (tid < 352){
    int n = tid>>4, t = (tid&15)*2;
    f32x2 a = {0.f,0.f};
    #pragma unroll 4
    for (int ff=0;ff<32;ff++){
      float lv = lhsS[n*32+ff];
      f32x2 w2 = *(const f32x2*)&W2[ff*32+t];
      a[0] = fmaf(lv, w2[0], a[0]); a[1] = fmaf(lv, w2[1], a[1]);
    }
    *(f32x2*)&lhs2[n*32+t] = a;
  }
  // ---- phase 10: rhsS[mm][t] = sum_u xw3[mm][u]*sm[u][t] ----
  if (tid < 352){
    int mm = tid>>4, t = (tid&15)*2;
    f32x2 a = {0.f,0.f};
    #pragma unroll 4
    for (int u=0;u<32;u++){
      float xv = xw3[mm*32+u];
      f32x2 smv = *(const f32x2*)&sm[u*32+t];
      a[0] = fmaf(xv, smv[0], a[0]); a[1] = fmaf(xv, smv[1], a[1]);
    }
    *(f32x2*)&rhsS[mm*32+t] = a;
  }
  __syncthreads();
  // ---- phase 11: sig2[a][l] = sigm(lhs2[a][:]·rhsS[l][:] + bs) ----
  if (tid < 484){
    int a_ = tid/22, l = tid - (tid/22)*22;
    const float4* lp = (const float4*)&lhs2[a_*32];
    const float4* rp = (const float4*)&rhsS[l*32];
    float p = 0.f;
    #pragma unroll
    for (int q=0;q<8;q++){
      float4 lv = lp[q], rv = rp[q];
      p = fmaf(lv.x, rv.x, p); p = fmaf(lv.y, rv.y, p);
      p = fmaf(lv.z, rv.z, p); p = fmaf(lv.w, rv.w, p);
    }
    sig2[tid] = sigm(p + bs[tid]);
  }
  __syncthreads();
  // ---- phase 12: Sl[n][l] = sum_mm Vs[n][mm]*sig2[mm][l] ----
  {
    int n = tid>>4, lp_ = tid&15;
    if (n < 22 && lp_ < 11){
      int l = lp_*2;
      f32x2 s = {0.f,0.f};
      #pragma unroll 2
      for (int mm=0;mm<22;mm++){
        float vv = Vs[n*22+mm];
        f32x2 sg = *(const f32x2*)&sig2[mm*22+l];
        s[0] = fmaf(vv, sg[0], s[0]); s[1] = fmaf(vv, sg[1], s[1]);
      }
      *(f32x2*)&Sl[n*22+l] = s;
    }
  }
  __syncthreads();
  // ---- spatial softmax over n (axis=1) ----
  {
    int grp = tid>>5, nn = tid&31;
    for (int l = grp; l < 22; l += 16){
      float v = (nn<22) ? Sl[nn*22 + l] : -1e30f;
      float mx = v;
      #pragma unroll
      for (int mask=1; mask<32; mask<<=1) mx = fmaxf(mx, __shfl_xor(mx, mask));
      float e = (nn<22) ? expf(v-mx) : 0.f;
      float s = e;
      #pragma unroll
      for (int mask=1; mask<32; mask<<=1) s += __shfl_xor(s, mask);
      if (nn<22) snorm[(size_t)b*484 + nn*22 + l] = e*(1.f/s);
    }
  }
}

// ---------------- Fused m-pair (R5 16x16 version — best measured, verbatim) ----------------
__global__ __launch_bounds__(256, 6) void k_fused(
    const float* __restrict__ x,
    const float* __restrict__ wsT, const float* __restrict__ snorm,
    const u16* __restrict__ thA, const u16* __restrict__ wA, const float* __restrict__ wsB,
    const float* __restrict__ lng, const float* __restrict__ lnb,
    float* __restrict__ out){
  __shared__ __align__(16) u16 GtU[2][32*72];   // G^T bf16 [t][64 cols], stride 72, swizzled blocks
  __shared__ __align__(16) u16 sgTU[2][34*72];  // sg^T bf16 [t+1][c], rows 0,33 zero
  __shared__ __align__(16) u16 xTU[2][32*40];   // x[m]^T bf16 [t][f], stride 40, swizzled blocks
  __shared__ __align__(16) float ak4[22*4];     // [n][mi*2+k1]
  __shared__ float smm[2];

  int wg = blockIdx.x;
  int logical = (wg & 7)*1408 + (wg >> 3);      // 11264 = 8*1408 XCD swizzle
  int b = logical/11, mp = logical - b*11;
  int m0 = mp*2;
  int tid = threadIdx.x;
  const float* xb = x + (size_t)b*22528;

  if (tid < 128){                                // zero sg pad rows 0, 33
    int mi = tid>>6, r6 = tid&63;
    int row = (r6>>5) ? 33 : 0, c2 = r6&31;
    *(unsigned*)&sgTU[mi][row*72 + c2*2] = 0u;
  }
  if (tid < 88){
    int n = tid>>2, j = tid&3;                  // j = mi*2 + k1
    int mi = j>>1, k1 = j&1;
    int m = m0 + mi;
    ak4[tid] = wsT[k1*484 + n*22 + m] * snorm[(size_t)b*484 + n*22 + m];
  }
  if (tid < 2) smm[tid] = snorm[(size_t)b*484 + (m0+tid)*23];
  __syncthreads();

  // ---- Phase A: float4 loads, XOR-swizzled transposed b16 writes ----
  {
    f32x2 acc[4][2];
    #pragma unroll
    for (int j=0;j<4;j++){ acc[j][0]=f32x2{0,0}; acc[j][1]=f32x2{0,0}; }
    const float4* x4 = (const float4*)xb;
    #pragma unroll 2
    for (int n=0;n<22;n++){
      float4 av = *(const float4*)&ak4[n*4];
      float4 xv = x4[n*256 + tid];
      f32x2 xlo = {xv.x, xv.y}, xhi2 = {xv.z, xv.w};
      f32x2 c0 = {av.x,av.x}, c1 = {av.y,av.y}, c2 = {av.z,av.z}, c3 = {av.w,av.w};
      acc[0][0] = __builtin_elementwise_fma(c0, xlo,  acc[0][0]);
      acc[0][1] = __builtin_elementwise_fma(c0, xhi2, acc[0][1]);
      acc[1][0] = __builtin_elementwise_fma(c1, xlo,  acc[1][0]);
      acc[1][1] = __builtin_elementwise_fma(c1, xhi2, acc[1][1]);
      acc[2][0] = __builtin_elementwise_fma(c2, xlo,  acc[2][0]);
      acc[2][1] = __builtin_elementwise_fma(c2, xhi2, acc[2][1]);
      acc[3][0] = __builtin_elementwise_fma(c3, xlo,  acc[3][0]);
      acc[3][1] = __builtin_elementwise_fma(c3, xhi2, acc[3][1]);
    }
    int ff = tid>>3, t7 = tid&7, t0 = t7*4;
    int w4 = ff>>3, f_low = ff&7;
    int gcol0 = 8*((0*4 + w4) ^ t7) + f_low;
    int gcol1 = 8*((1*4 + w4) ^ t7) + f_low;
    int xcol  = 8*(w4 ^ (t7&3)) + f_low;
    #pragma unroll
    for (int mi=0;mi<2;mi++){
      float4 xm = ((const float4*)xb)[(m0+mi)*256 + tid];
      u16* xd = &xTU[mi][0];
      xd[(t0+0)*40 + xcol] = f2bf(xm.x);
      xd[(t0+1)*40 + xcol] = f2bf(xm.y);
      xd[(t0+2)*40 + xcol] = f2bf(xm.z);
      xd[(t0+3)*40 + xcol] = f2bf(xm.w);
      #pragma unroll
      for (int k1=0;k1<2;k1++){
        int j = mi*2 + k1;
        int gc = k1 ? gcol1 : gcol0;
        u16* gd = &GtU[mi][gc];
        gd[(t0+0)*72] = f2bf(acc[j][0][0]);
        gd[(t0+1)*72] = f2bf(acc[j][0][1]);
        gd[(t0+2)*72] = f2bf(acc[j][1][0]);
        gd[(t0+3)*72] = f2bf(acc[j][1][1]);
      }
    }
  }
  __syncthreads();

  int w = tid>>6, l = tid&63, r = l&15, g = l>>4;

  // ---- Phase B: sg = relu( Theta12^T G + smm * Theta0^T x ) ----
  {
    const u16* tA = thA + (size_t)(w*64 + l)*8;
    short8 a0 = *(const short8*)(tA);
    short8 a1 = *(const short8*)(tA + 2048);
    short8 a2 = *(const short8*)(tA + 4096);
    #pragma unroll
    for (int mi=0;mi<2;mi++){
      float sm_ = smm[mi];
      #pragma unroll
      for (int ti=0; ti<2; ++ti){
        int row = ti*16 + r;
        int h  = (row>>2)&7;
        int h2 = (row>>2)&3;
        f32x4 a12 = {0.f,0.f,0.f,0.f}, ax = {0.f,0.f,0.f,0.f};
        const u16* gp0 = &GtU[mi][row*72 + 8*((0*4+g)^h)];
        const u16* gp1 = &GtU[mi][row*72 + 8*((1*4+g)^h)];
        a12 = __builtin_amdgcn_mfma_f32_16x16x32_bf16(a1, *(const short8*)(gp0), a12, 0,0,0);
        a12 = __builtin_amdgcn_mfma_f32_16x16x32_bf16(a2, *(const short8*)(gp1), a12, 0,0,0);
        const u16* xp = &xTU[mi][row*40 + 8*(g^h2)];
        ax  = __builtin_amdgcn_mfma_f32_16x16x32_bf16(a0, *(const short8*)(xp),  ax,  0,0,0);
        int orow = 1 + row, c0 = w*16 + g*4;
        float v0 = fmaxf(fmaf(sm_, ax[0], a12[0]), 0.f);
        float v1 = fmaxf(fmaf(sm_, ax[1], a12[1]), 0.f);
        float v2 = fmaxf(fmaf(sm_, ax[2], a12[2]), 0.f);
        float v3 = fmaxf(fmaf(sm_, ax[3], a12[3]), 0.f);
        *(unsigned*)&sgTU[mi][orow*72 + c0]     = f2bf2(v0, v1);
        *(unsigned*)&sgTU[mi][orow*72 + c0 + 2] = f2bf2(v2, v3);
      }
    }
  }
  __syncthreads();

  // ---- Phase C: y[o][t] = sum_k W[k][o]*B[k][t], K=224 ----
  f32x4 acc[2][2];
  acc[0][0]=f32x4{0,0,0,0}; acc[0][1]=f32x4{0,0,0,0};
  acc[1][0]=f32x4{0,0,0,0}; acc[1][1]=f32x4{0,0,0,0};
  {
    const u16* pA = wA + (size_t)(w*64 + l)*8;
    #pragma unroll
    for (int ks=0; ks<6; ++ks){
      short8 wk = *(const short8*)(pA + ks*2048);
      int seg = ks>>1, colb = (ks&1)*32 + 8*g;
      #pragma unroll
      for (int mi=0;mi<2;mi++){
        const u16* q0 = &sgTU[mi][(r + seg)*72 + colb];
        acc[mi][0] = __builtin_amdgcn_mfma_f32_16x16x32_bf16(wk, *(const short8*)(q0),         acc[mi][0], 0,0,0);
        acc[mi][1] = __builtin_amdgcn_mfma_f32_16x16x32_bf16(wk, *(const short8*)(q0 + 16*72), acc[mi][1], 0,0,0);
      }
    }
    short8 wk = *(const short8*)(pA + 6*2048);
    int h2 = (r>>2)&3;
    #pragma unroll
    for (int mi=0;mi<2;mi++){
      const u16* q = &xTU[mi][r*40 + 8*(g^h2)];
      acc[mi][0] = __builtin_amdgcn_mfma_f32_16x16x32_bf16(wk, *(const short8*)(q),         acc[mi][0], 0,0,0);
      acc[mi][1] = __builtin_amdgcn_mfma_f32_16x16x32_bf16(wk, *(const short8*)(q + 16*40), acc[mi][1], 0,0,0);
    }
  }

  // ---- Epilogue: bias + relu + LN over o per t, both m ----
  float4 bias4 = ((const float4*)wsB)[w*4 + g];
  float bb[4] = {bias4.x, bias4.y, bias4.z, bias4.w};
  float y[2][2][4];
  float s1[2][2] = {{0.f,0.f},{0.f,0.f}}, s2[2][2] = {{0.f,0.f},{0.f,0.f}};
  #pragma unroll
  for (int mi=0;mi<2;mi++){
    #pragma unroll
    for (int h=0;h<2;h++){
      #pragma unroll
      for (int i=0;i<4;i++){
        float v = fmaxf(acc[mi][h][i] + bb[i], 0.f);
        y[mi][h][i] = v;
        s1[mi][h] += v;
        s2[mi][h] = fmaf(v, v, s2[mi][h]);
      }
      s1[mi][h] += __shfl_xor(s1[mi][h],16); s1[mi][h] += __shfl_xor(s1[mi][h],32);
      s2[mi][h] += __shfl_xor(s2[mi][h],16); s2[mi][h] += __shfl_xor(s2[mi][h],32);
    }
  }
  float* p1 = (float*)&GtU[0][0];
  float* p2 = p1 + 256;
  if (l < 16){
    #pragma unroll
    for (int mi=0;mi<2;mi++){
      p1[(mi*32 + l)*4 + w]      = s1[mi][0];
      p1[(mi*32 + 16 + l)*4 + w] = s1[mi][1];
      p2[(mi*32 + l)*4 + w]      = s2[mi][0];
      p2[(mi*32 + 16 + l)*4 + w] = s2[mi][1];
    }
  }
  __syncthreads();
  float4 g4 = ((const float4*)lng)[w*4 + g];
  float4 b4 = ((const float4*)lnb)[w*4 + g];
  float gg[4]={g4.x,g4.y,g4.z,g4.w}, bgg[4]={b4.x,b4.y,b4.z,b4.w};
  #pragma unroll
  for (int mi=0;mi<2;mi++){
    float4 q1a = ((const float4*)p1)[mi*32 + r],      q2a = ((const float4*)p2)[mi*32 + r];
    float4 q1b = ((const float4*)p1)[mi*32 + 16 + r], q2b = ((const float4*)p2)[mi*32 + 16 + r];
    float S1a = q1a.x+q1a.y+q1a.z+q1a.w, S2a = q2a.x+q2a.y+q2a.z+q2a.w;
    float S1b = q1b.x+q1b.y+q1b.z+q1b.w, S2b = q2b.x+q2b.y+q2b.z+q2b.w;
    float mu0 = S1a*(1.f/64.f), var0 = S2a*(1.f/64.f) - mu0*mu0, rs0 = rsqrtf(var0 + 1e-5f);
    float mu1 = S1b*(1.f/64.f), var1 = S2b*(1.f/64.f) - mu1*mu1, rs1 = rsqrtf(var1 + 1e-5f);
    float* ob = out + ((size_t)(b*22 + m0 + mi)*64 + (w*16 + g*4))*32;
    #pragma unroll
    for (int i=0;i<4;i++){
      ob[i*32 + r]      = (y[mi][0][i]-mu0)*rs0*gg[i] + bgg[i];
      ob[i*32 + 16 + r] = (y[mi][1][i]-mu1)*rs1*gg[i] + bgg[i];
    }
  }
}

extern "C" void kernel_launch(void* const* d_in, const int* in_sizes, int n_in,
                              void* d_out, int out_size, void* d_ws, size_t ws_size,
                              hipStream_t stream){
  const float* x     = (const float*)d_in[0];
  const float* U1    = (const float*)d_in[1];
  const float* U2    = (const float*)d_in[2];
  const float* U3    = (const float*)d_in[3];
  const float* be    = (const float*)d_in[4];
  const float* Ve    = (const float*)d_in[5];
  const float* W1    = (const float*)d_in[6];
  const float* W2    = (const float*)d_in[7];
  const float* W3    = (const float*)d_in[8];
  const float* bs    = (const float*)d_in[9];
  const float* Vs    = (const float*)d_in[10];
  const float* Theta = (const float*)d_in[11];
  const float* emb   = (const float*)d_in[12];
  const float* tw    = (const float*)d_in[13];
  const float* tb    = (const float*)d_in[14];
  const float* rw    = (const float*)d_in[15];
  const float* rb    = (const float*)d_in[16];
  const float* lng   = (const float*)d_in[17];
  const float* lnb   = (const float*)d_in[18];
  float* out = (float*)d_out;
  float* wsf = (float*)d_ws;
  float* wsT   = wsf;                        // 1024 floats
  float* snorm = wsf + 1024;                 // 495616 floats
  u16*   thA   = (u16*)(wsf + 496640);       // 6144 u16
  u16*   wA    = (u16*)(wsf + 499712);       // 14336 u16
  float* wsB   = wsf + 506880;               // 64 floats

  k_sup_prep<<<82, 256, 0, stream>>>(emb, wsT, Theta, tw, tb, rw, rb, thA, wA, wsB);
  k_attn<<<1024, 512, 0, stream>>>(x, U1,U2,U3, be,Ve, W1,W2,W3, bs,Vs, snorm);
  k_fused<<<1024*11, 256, 0, stream>>>(x, wsT, snorm, thA, wA, wsB, lng, lnb, out);
}

// Round 14
// 152.644 us; speedup vs baseline: 1.0398x; 1.0398x over previous
//
#include <hip/hip_runtime.h>
#include <hip/hip_bf16.h>
#include <math.h>

// B=1024, N=22, F_IN=32, T=32, K=3, CHEV=64, TIMEF=64
// x[b,n,f,t]: b-stride 22528, n-stride 1024, f-stride 32

typedef unsigned short u16;
typedef __attribute__((ext_vector_type(8))) short short8;
typedef __attribute__((ext_vector_type(4))) float f32x4;
typedef __attribute__((ext_vector_type(2))) float f32x2;

__device__ __forceinline__ float sigm(float v){ return 1.f/(1.f+expf(-v)); }

__device__ __forceinline__ u16 f2bf(float x){
  __hip_bfloat16 h = __float2bfloat16(x);
  return *reinterpret_cast<u16*>(&h);
}
__device__ __forceinline__ unsigned f2bf2(float lo, float hi){
  return (unsigned)f2bf(lo) | ((unsigned)f2bf(hi) << 16);
}

// ---------------- K_prep (blocks 0..80, 16x16 fragment packing) + supports (block 81) ----
__global__ void k_sup_prep(const float* __restrict__ emb, float* __restrict__ wsT,
                           const float* __restrict__ Theta,
                           const float* __restrict__ tw, const float* __restrict__ tb,
                           const float* __restrict__ rw, const float* __restrict__ rb,
                           u16* __restrict__ thA, u16* __restrict__ wA, float* __restrict__ wsB){
  if (blockIdx.x < 81){
    int tid = blockIdx.x*256 + threadIdx.x;
    if (tid < 6144){
      int j = tid&7, l = (tid>>3)&63, blk = tid>>9;      // blk 0..11
      int ks = blk>>2, ci = blk&3, r = l&15, g = l>>4;
      int kf = 32*ks + 8*g + j, c = 16*ci + r;
      thA[tid] = f2bf(Theta[kf*64 + c]);
    } else if (tid < 20480){
      int e = tid - 6144;
      int j = e&7, l = (e>>3)&63, blk = e>>9;            // blk 0..27
      int ks = blk>>2, oi = blk&3, r = l&15, g = l>>4;
      int k = 32*ks + 8*g + j, o = 16*oi + r;
      float v = (k < 192) ? tw[o*192 + (k&63)*3 + (k>>6)] : rw[o*32 + (k-192)];
      wA[e] = f2bf(v);
    } else if (tid < 20544){
      int o = tid - 20480; wsB[o] = tb[o] + rb[o];
    }
    return;
  }
  __shared__ float M[484];
  __shared__ float T1s[484];
  int tid = threadIdx.x;
  for (int idx=tid; idx<484; idx+=256){
    int n = idx/22, m = idx - (idx/22)*22;
    float s = 0.f;
    for (int j=0;j<22;j++) s += emb[n*22+j]*emb[m*22+j];
    M[idx] = fmaxf(s, 0.f);
  }
  __syncthreads();
  if (tid < 22){
    float mx = -1e30f;
    for (int m=0;m<22;m++) mx = fmaxf(mx, M[tid*22+m]);
    float s = 0.f;
    for (int m=0;m<22;m++) s += expf(M[tid*22+m]-mx);
    float inv = 1.f/s;
    for (int m=0;m<22;m++) T1s[tid*22+m] = expf(M[tid*22+m]-mx)*inv;
  }
  __syncthreads();
  for (int idx=tid; idx<484; idx+=256){
    int n = idx/22, m = idx - (idx/22)*22;
    float s = 0.f;
    for (int p=0;p<22;p++) s += T1s[n*22+p]*T1s[p*22+m];
    wsT[idx]      = T1s[idx];
    wsT[484+idx]  = 2.f*s - ((n==m)?1.f:0.f);
  }
}

// ---------------- K12: temporal + spatial attention -> S_norm (R6-exact, best measured) ----
__global__ __launch_bounds__(512) void k_attn(
    const float* __restrict__ x,
    const float* __restrict__ U1, const float* __restrict__ U2, const float* __restrict__ U3,
    const float* __restrict__ be, const float* __restrict__ Ve,
    const float* __restrict__ W1, const float* __restrict__ W2, const float* __restrict__ W3,
    const float* __restrict__ bs, const float* __restrict__ Vs,
    float* __restrict__ snorm){
  int b = blockIdx.x, tid = threadIdx.x;
  const float* xb = x + (size_t)b*22528;
  __shared__ float xu1[1024];
  __shared__ float rhs_t[704];
  __shared__ float lhs_t[704];
  __shared__ float sigp[1024];
  __shared__ float Em[1024];
  __shared__ float sm[1024];
  __shared__ float w1e[32];
  __shared__ float xw3[704];
  __shared__ float lhsS[704];
  __shared__ float lhs2[704];
  __shared__ float rhsS[704];
  __shared__ float sig2[484];
  __shared__ float Sl[484];

  for (int idx=tid; idx<1024; idx+=512){
    float a=0.f;
    for (int n=0;n<22;n++) a = fmaf(xb[n*1024 + idx], U1[n], a);
    xu1[idx]=a;
  }
  for (int idx=tid; idx<704; idx+=512){
    int n = idx>>5, t = idx&31; float a=0.f, c=0.f;
    for (int f=0;f<32;f++){ float xv = xb[n*1024+f*32+t]; a = fmaf(U3[f],xv,a); c = fmaf(W3[f],xv,c); }
    rhs_t[idx]=a; xw3[idx]=c;
  }
  __syncthreads();
  for (int idx=tid; idx<704; idx+=512){
    int t = idx/22, n2 = idx - t*22; float a=0.f;
    for (int f=0;f<32;f++) a = fmaf(xu1[f*32+t], U2[f*22+n2], a);
    lhs_t[idx]=a;
  }
  __syncthreads();
  for (int idx=tid; idx<1024; idx+=512){
    int s = idx>>5, u = idx&31; float p=0.f;
    for (int n=0;n<22;n++) p = fmaf(lhs_t[s*22+n], rhs_t[n*32+u], p);
    sigp[idx] = sigm(p + be[idx]);
  }
  __syncthreads();
  for (int idx=tid; idx<1024; idx+=512){
    int t = idx>>5, u = idx&31; float a=0.f;
    for (int s2=0;s2<32;s2++) a = fmaf(Ve[t*32+s2], sigp[s2*32+u], a);
    Em[idx]=a;
  }
  __syncthreads();
  {
    int u = tid>>4, th = tid&15;
    float e0 = Em[(2*th)*32 + u], e1 = Em[(2*th+1)*32 + u];
    float mx = fmaxf(e0, e1);
    #pragma unroll
    for (int mask=1; mask<16; mask<<=1) mx = fmaxf(mx, __shfl_xor(mx, mask));
    float x0 = expf(e0-mx), x1 = expf(e1-mx);
    float s = x0 + x1;
    #pragma unroll
    for (int mask=1; mask<16; mask<<=1) s += __shfl_xor(s, mask);
    float inv = 1.f/s;
    sm[(2*th)*32 + u]   = x0*inv;
    sm[(2*th+1)*32 + u] = x1*inv;
  }
  __syncthreads();
  {
    int u = tid>>4, th = tid&15;
    float pw = fmaf(sm[u*32 + 2*th], W1[2*th], sm[u*32 + 2*th+1]*W1[2*th+1]);
    #pragma unroll
    for (int mask=1; mask<16; mask<<=1) pw += __shfl_xor(pw, mask);
    if (th==0) w1e[u] = pw;
  }
  __syncthreads();
  for (int idx=tid; idx<704; idx+=512){
    int n = idx>>5, f = idx&31; float a=0.f;
    for (int u=0;u<32;u++) a = fmaf(xb[n*1024+f*32+u], w1e[u], a);
    lhsS[idx]=a;
  }
  __syncthreads();
  for (int idx=tid; idx<704; idx+=512){
    int n = idx>>5, t = idx&31; float a=0.f;
    for (int f=0;f<32;f++) a = fmaf(lhsS[n*32+f], W2[f*32+t], a);
    lhs2[idx]=a;
  }
  for (int idx=tid; idx<704; idx+=512){
    int mm = idx>>5, t = idx&31; float a=0.f;
    for (int u=0;u<32;u++) a = fmaf(xw3[mm*32+u], sm[u*32+t], a);
    rhsS[idx]=a;
  }
  __syncthreads();
  for (int idx=tid; idx<484; idx+=512){
    int a_ = idx/22, l = idx - (idx/22)*22; float p=0.f;
    for (int t=0;t<32;t++) p = fmaf(lhs2[a_*32+t], rhsS[l*32+t], p);
    sig2[idx] = sigm(p + bs[idx]);
  }
  __syncthreads();
  for (int idx=tid; idx<484; idx+=512){
    int n = idx/22, l = idx - (idx/22)*22; float s=0.f;
    for (int mm=0;mm<22;mm++) s = fmaf(Vs[n*22+mm], sig2[mm*22+l], s);
    Sl[idx]=s;
  }
  __syncthreads();
  {
    int grp = tid>>5, nn = tid&31;
    for (int l = grp; l < 22; l += 16){
      float v = (nn<22) ? Sl[nn*22 + l] : -1e30f;
      float mx = v;
      #pragma unroll
      for (int mask=1; mask<32; mask<<=1) mx = fmaxf(mx, __shfl_xor(mx, mask));
      float e = (nn<22) ? expf(v-mx) : 0.f;
      float s = e;
      #pragma unroll
      for (int mask=1; mask<32; mask<<=1) s += __shfl_xor(s, mask);
      if (nn<22) snorm[(size_t)b*484 + nn*22 + l] = e*(1.f/s);
    }
  }
}

// ---------------- Fused m-pair, corrected LDS swizzles ----------------
// GtU/xTU write key: rho = t7>>1  (bank-group = 16(t7&1)+4(blk^(t7>>1)) spans all 8 exactly once)
// GtU/xTU read key:  (row>>3)    sgTU block-swizzle: rho(row) = (row>>1)&7 (rho(row+16)==rho(row))
__global__ __launch_bounds__(256, 6) void k_fused(
    const float* __restrict__ x,
    const float* __restrict__ wsT, const float* __restrict__ snorm,
    const u16* __restrict__ thA, const u16* __restrict__ wA, const float* __restrict__ wsB,
    const float* __restrict__ lng, const float* __restrict__ lnb,
    float* __restrict__ out){
  __shared__ __align__(16) u16 GtU[2][32*72];   // G^T bf16 [t][8 blocks of 8], stride 72
  __shared__ __align__(16) u16 sgTU[2][34*72];  // sg^T bf16 [t+1][8 blocks of 8], rows 0,33 zero
  __shared__ __align__(16) u16 xTU[2][32*40];   // x[m]^T bf16 [t][4 blocks of 8], stride 40
  __shared__ __align__(16) float ak4[22*4];     // [n][mi*2+k1]
  __shared__ float smm[2];

  int wg = blockIdx.x;
  int logical = (wg & 7)*1408 + (wg >> 3);      // 11264 = 8*1408 XCD swizzle
  int b = logical/11, mp = logical - b*11;
  int m0 = mp*2;
  int tid = threadIdx.x;
  const float* xb = x + (size_t)b*22528;

  if (tid < 128){                                // zero sg pad rows 0, 33
    int mi = tid>>6, r6 = tid&63;
    int row = (r6>>5) ? 33 : 0, c2 = r6&31;
    *(unsigned*)&sgTU[mi][row*72 + c2*2] = 0u;
  }
  if (tid < 88){
    int n = tid>>2, j = tid&3;                  // j = mi*2 + k1
    int mi = j>>1, k1 = j&1;
    int m = m0 + mi;
    ak4[tid] = wsT[k1*484 + n*22 + m] * snorm[(size_t)b*484 + n*22 + m];
  }
  if (tid < 2) smm[tid] = snorm[(size_t)b*484 + (m0+tid)*23];
  __syncthreads();

  // ---- Phase A: float4 loads, rho=t7>>1 swizzled transposed b16 writes ----
  {
    f32x2 acc[4][2];
    #pragma unroll
    for (int j=0;j<4;j++){ acc[j][0]=f32x2{0,0}; acc[j][1]=f32x2{0,0}; }
    const float4* x4 = (const float4*)xb;
    #pragma unroll 2
    for (int n=0;n<22;n++){
      float4 av = *(const float4*)&ak4[n*4];
      float4 xv = x4[n*256 + tid];
      f32x2 xlo = {xv.x, xv.y}, xhi2 = {xv.z, xv.w};
      f32x2 c0 = {av.x,av.x}, c1 = {av.y,av.y}, c2 = {av.z,av.z}, c3 = {av.w,av.w};
      acc[0][0] = __builtin_elementwise_fma(c0, xlo,  acc[0][0]);
      acc[0][1] = __builtin_elementwise_fma(c0, xhi2, acc[0][1]);
      acc[1][0] = __builtin_elementwise_fma(c1, xlo,  acc[1][0]);
      acc[1][1] = __builtin_elementwise_fma(c1, xhi2, acc[1][1]);
      acc[2][0] = __builtin_elementwise_fma(c2, xlo,  acc[2][0]);
      acc[2][1] = __builtin_elementwise_fma(c2, xhi2, acc[2][1]);
      acc[3][0] = __builtin_elementwise_fma(c3, xlo,  acc[3][0]);
      acc[3][1] = __builtin_elementwise_fma(c3, xhi2, acc[3][1]);
    }
    int f = tid>>3, t7 = tid&7, t0 = t7*4;
    int w4 = f>>3, f_low = f&7;
    int rho = t7>>1;                            // 0..3
    int gcol0 = 8*((0*4 + w4) ^ rho) + f_low;
    int gcol1 = 8*((1*4 + w4) ^ rho) + f_low;
    int xcol  = 8*(w4 ^ rho) + f_low;
    #pragma unroll
    for (int mi=0;mi<2;mi++){
      float4 xm = ((const float4*)xb)[(m0+mi)*256 + tid];
      u16* xd = &xTU[mi][0];
      xd[(t0+0)*40 + xcol] = f2bf(xm.x);
      xd[(t0+1)*40 + xcol] = f2bf(xm.y);
      xd[(t0+2)*40 + xcol] = f2bf(xm.z);
      xd[(t0+3)*40 + xcol] = f2bf(xm.w);
      #pragma unroll
      for (int k1=0;k1<2;k1++){
        int j = mi*2 + k1;
        int gc = k1 ? gcol1 : gcol0;
        u16* gd = &GtU[mi][gc];
        gd[(t0+0)*72] = f2bf(acc[j][0][0]);
        gd[(t0+1)*72] = f2bf(acc[j][0][1]);
        gd[(t0+2)*72] = f2bf(acc[j][1][0]);
        gd[(t0+3)*72] = f2bf(acc[j][1][1]);
      }
    }
  }
  __syncthreads();

  int w = tid>>6, l = tid&63, r = l&15, g = l>>4;

  // ---- Phase B: sg = relu( Theta12^T G + smm * Theta0^T x ) ----
  {
    const u16* tA = thA + (size_t)(w*64 + l)*8;
    short8 a0 = *(const short8*)(tA);
    short8 a1 = *(const short8*)(tA + 2048);
    short8 a2 = *(const short8*)(tA + 4096);
    #pragma unroll
    for (int mi=0;mi<2;mi++){
      float sm_ = smm[mi];
      #pragma unroll
      for (int ti=0; ti<2; ++ti){
        int row = ti*16 + r;
        int h  = (row>>3)&3;                    // GtU read key (matches rho=t7>>1)
        f32x4 a12 = {0.f,0.f,0.f,0.f}, ax = {0.f,0.f,0.f,0.f};
        const u16* gp0 = &GtU[mi][row*72 + 8*((0*4+g)^h)];
        const u16* gp1 = &GtU[mi][row*72 + 8*((1*4+g)^h)];
        a12 = __builtin_amdgcn_mfma_f32_16x16x32_bf16(a1, *(const short8*)(gp0), a12, 0,0,0);
        a12 = __builtin_amdgcn_mfma_f32_16x16x32_bf16(a2, *(const short8*)(gp1), a12, 0,0,0);
        const u16* xp = &xTU[mi][row*40 + 8*(g^h)];
        ax  = __builtin_amdgcn_mfma_f32_16x16x32_bf16(a0, *(const short8*)(xp),  ax,  0,0,0);
        int orow = 1 + row;
        int sblk = 2*w + (g>>1), soff = 4*(g&1);
        u16* srow = &sgTU[mi][orow*72 + 8*(sblk ^ ((orow>>1)&7)) + soff];
        float v0 = fmaxf(fmaf(sm_, ax[0], a12[0]), 0.f);
        float v1 = fmaxf(fmaf(sm_, ax[1], a12[1]), 0.f);
        float v2 = fmaxf(fmaf(sm_, ax[2], a12[2]), 0.f);
        float v3 = fmaxf(fmaf(sm_, ax[3], a12[3]), 0.f);
        *(unsigned*)&srow[0] = f2bf2(v0, v1);
        *(unsigned*)&srow[2] = f2bf2(v2, v3);
      }
    }
  }
  __syncthreads();

  // ---- Phase C: y[o][t] = sum_k W[k][o]*B[k][t], K=224 ----
  f32x4 acc[2][2];
  acc[0][0]=f32x4{0,0,0,0}; acc[0][1]=f32x4{0,0,0,0};
  acc[1][0]=f32x4{0,0,0,0}; acc[1][1]=f32x4{0,0,0,0};
  {
    const u16* pA = wA + (size_t)(w*64 + l)*8;
    #pragma unroll
    for (int ks=0; ks<6; ++ks){
      short8 wk = *(const short8*)(pA + ks*2048);
      int seg = ks>>1;
      int blkR = 4*(ks&1) + g;
      int row2 = r + seg;
      #pragma unroll
      for (int mi=0;mi<2;mi++){
        // rho(row2+16) == rho(row2) since ((row+16)>>1)&7 == ((row>>1)+8)&7... both shift by 8 ≡ 0 mod 8
        const u16* q0 = &sgTU[mi][row2*72 + 8*(blkR ^ ((row2>>1)&7))];
        acc[mi][0] = __builtin_amdgcn_mfma_f32_16x16x32_bf16(wk, *(const short8*)(q0),         acc[mi][0], 0,0,0);
        acc[mi][1] = __builtin_amdgcn_mfma_f32_16x16x32_bf16(wk, *(const short8*)(q0 + 16*72), acc[mi][1], 0,0,0);
      }
    }
    short8 wk = *(const short8*)(pA + 6*2048);
    int hx0 = (r>>3)&3;
    int hx1 = (hx0 + 2)&3;                      // key for row r+16
    #pragma unroll
    for (int mi=0;mi<2;mi++){
      const u16* qx0 = &xTU[mi][r*40       + 8*(g^hx0)];
      const u16* qx1 = &xTU[mi][(r+16)*40  + 8*(g^hx1)];
      acc[mi][0] = __builtin_amdgcn_mfma_f32_16x16x32_bf16(wk, *(const short8*)(qx0), acc[mi][0], 0,0,0);
      acc[mi][1] = __builtin_amdgcn_mfma_f32_16x16x32_bf16(wk, *(const short8*)(qx1), acc[mi][1], 0,0,0);
    }
  }

  // ---- Epilogue: bias + relu + LN over o per t, both m ----
  float4 bias4 = ((const float4*)wsB)[w*4 + g];
  float bb[4] = {bias4.x, bias4.y, bias4.z, bias4.w};
  float y[2][2][4];
  float s1[2][2] = {{0.f,0.f},{0.f,0.f}}, s2[2][2] = {{0.f,0.f},{0.f,0.f}};
  #pragma unroll
  for (int mi=0;mi<2;mi++){
    #pragma unroll
    for (int h=0;h<2;h++){
      #pragma unroll
      for (int i=0;i<4;i++){
        float v = fmaxf(acc[mi][h][i] + bb[i], 0.f);
        y[mi][h][i] = v;
        s1[mi][h] += v;
        s2[mi][h] = fmaf(v, v, s2[mi][h]);
      }
      s1[mi][h] += __shfl_xor(s1[mi][h],16); s1[mi][h] += __shfl_xor(s1[mi][h],32);
      s2[mi][h] += __shfl_xor(s2[mi][h],16); s2[mi][h] += __shfl_xor(s2[mi][h],32);
    }
  }
  float* p1 = (float*)&GtU[0][0];
  float* p2 = p1 + 256;
  if (l < 16){
    #pragma unroll
    for (int mi=0;mi<2;mi++){
      p1[(mi*32 + l)*4 + w]      = s1[mi][0];
      p1[(mi*32 + 16 + l)*4 + w] = s1[mi][1];
      p2[(mi*32 + l)*4 + w]      = s2[mi][0];
      p2[(mi*32 + 16 + l)*4 + w] = s2[mi][1];
    }
  }
  __syncthreads();
  float4 g4 = ((const float4*)lng)[w*4 + g];
  float4 b4 = ((const float4*)lnb)[w*4 + g];
  float gg[4]={g4.x,g4.y,g4.z,g4.w}, bgg[4]={b4.x,b4.y,b4.z,b4.w};
  #pragma unroll
  for (int mi=0;mi<2;mi++){
    float4 q1a = ((const float4*)p1)[mi*32 + r],      q2a = ((const float4*)p2)[mi*32 + r];
    float4 q1b = ((const float4*)p1)[mi*32 + 16 + r], q2b = ((const float4*)p2)[mi*32 + 16 + r];
    float S1a = q1a.x+q1a.y+q1a.z+q1a.w, S2a = q2a.x+q2a.y+q2a.z+q2a.w;
    float S1b = q1b.x+q1b.y+q1b.z+q1b.w, S2b = q2b.x+q2b.y+q2b.z+q2b.w;
    float mu0 = S1a*(1.f/64.f), var0 = S2a*(1.f/64.f) - mu0*mu0, rs0 = rsqrtf(var0 + 1e-5f);
    float mu1 = S1b*(1.f/64.f), var1 = S2b*(1.f/64.f) - mu1*mu1, rs1 = rsqrtf(var1 + 1e-5f);
    float* ob = out + ((size_t)(b*22 + m0 + mi)*64 + (w*16 + g*4))*32;
    #pragma unroll
    for (int i=0;i<4;i++){
      ob[i*32 + r]      = (y[mi][0][i]-mu0)*rs0*gg[i] + bgg[i];
      ob[i*32 + 16 + r] = (y[mi][1][i]-mu1)*rs1*gg[i] + bgg[i];
    }
  }
}

extern "C" void kernel_launch(void* const* d_in, const int* in_sizes, int n_in,
                              void* d_out, int out_size, void* d_ws, size_t ws_size,
                              hipStream_t stream){
  const float* x     = (const float*)d_in[0];
  const float* U1    = (const float*)d_in[1];
  const float* U2    = (const float*)d_in[2];
  const float* U3    = (const float*)d_in[3];
  const float* be    = (const float*)d_in[4];
  const float* Ve    = (const float*)d_in[5];
  const float* W1    = (const float*)d_in[6];
  const float* W2    = (const float*)d_in[7];
  const float* W3    = (const float*)d_in[8];
  const float* bs    = (const float*)d_in[9];
  const float* Vs    = (const float*)d_in[10];
  const float* Theta = (const float*)d_in[11];
  const float* emb   = (const float*)d_in[12];
  const float* tw    = (const float*)d_in[13];
  const float* tb    = (const float*)d_in[14];
  const float* rw    = (const float*)d_in[15];
  const float* rb    = (const float*)d_in[16];
  const float* lng   = (const float*)d_in[17];
  const float* lnb   = (const float*)d_in[18];
  float* out = (float*)d_out;
  float* wsf = (float*)d_ws;
  float* wsT   = wsf;                        // 1024 floats
  float* snorm = wsf + 1024;                 // 495616 floats
  u16*   thA   = (u16*)(wsf + 496640);       // 6144 u16
  u16*   wA    = (u16*)(wsf + 499712);       // 14336 u16
  float* wsB   = wsf + 506880;               // 64 floats

  k_sup_prep<<<82, 256, 0, stream>>>(emb, wsT, Theta, tw, tb, rw, rb, thA, wA, wsB);
  k_attn<<<1024, 512, 0, stream>>>(x, U1,U2,U3, be,Ve, W1,W2,W3, bs,Vs, snorm);
  k_fused<<<1024*11, 256, 0, stream>>>(x, wsT, snorm, thA, wA, wsB, lng, lnb, out);
}